// Round 18
// baseline (179.353 us; speedup 1.0000x reference)
//
#include <hip/hip_runtime.h>
#include <stdint.h>

#define N_ROWS 262144
#define D_OUTC 128
#define M_MOD  64
#define T_CTX  16

// ---- workspace layout (bytes) ----
#define ZB_OFF   ((size_t)0)
#define ZB_BYTES ((size_t)M_MOD * N_ROWS * 2)          // Zbt[m][n] f16  33.5MB
#define WT_OFF   (ZB_OFF + ZB_BYTES)
#define WT_BYTES ((size_t)T_CTX * N_ROWS * 2)          // Wt[t][n] f16  8.4MB
#define SS_OFF   (WT_OFF + WT_BYTES)
#define SS_BYTES ((size_t)T_CTX * M_MOD * M_MOD * 4)
#define B_OFF    (SS_OFF + SS_BYTES)
#define B_BYTES  ((size_t)T_CTX * M_MOD * 4)
#define WSUM_OFF (B_OFF + B_BYTES)
#define WSUM_BYTES ((size_t)64)
#define LT_OFF   (WSUM_OFF + WSUM_BYTES)
#define LT_BYTES ((size_t)64)
#define CNT_OFF  (LT_OFF + LT_BYTES)
#define CNT_BYTES ((size_t)64)
#define PSS_OFF  (CNT_OFF + CNT_BYTES)
#define PSS_BYTES ((size_t)256 * T_CTX * M_MOD * M_MOD * 2)  // 33.5MB bf16 partials
#define NEED_BIG (PSS_OFF + PSS_BYTES)

typedef __attribute__((ext_vector_type(4))) float f32x4;
typedef __attribute__((ext_vector_type(8))) _Float16 f16x8;
typedef __attribute__((ext_vector_type(2))) _Float16 h2;

union FR { uint4 u; f16x8 v; h2 h[4]; };

__device__ __forceinline__ float bf2f(unsigned short u) {
  return __uint_as_float(((unsigned int)u) << 16);
}
__device__ __forceinline__ unsigned short f2bf(float f) {
  unsigned int x = __float_as_uint(f);
  return (unsigned short)((x + 0x7fffu + ((x >> 16) & 1u)) >> 16);
}
__device__ __forceinline__ h2 cvt_pkrtz(float a, float b) {
  return __builtin_bit_cast(h2, __builtin_amdgcn_cvt_pkrtz(a, b));
}
#if __has_builtin(__builtin_amdgcn_fdot2)
__device__ __forceinline__ float fdot2f(h2 a, h2 b, float c) {
  return __builtin_amdgcn_fdot2(a, b, c, false);
}
#else
__device__ __forceinline__ float fdot2f(h2 a, h2 b, float c) {
  return c + (float)a[0] * (float)b[0] + (float)a[1] * (float)b[1];
}
#endif

#define WAITVM(N) asm volatile("s_waitcnt vmcnt(" #N ")" ::: "memory")
#define SBAR() do { __builtin_amdgcn_s_barrier(); __builtin_amdgcn_sched_barrier(0); } while (0)

// ================ zk: Z^T = (Mp @ Y^T) via f16 MFMA; also Wt; block0 zeroes Bm/wsum/cnt ====
__global__ __launch_bounds__(256, 3) void zk_kernel(
    const float* __restrict__ Y, const float* __restrict__ Mp,
    const float* __restrict__ W,
    _Float16* __restrict__ Zbt, _Float16* __restrict__ Wt,
    float* __restrict__ Bm0 /* Bm..wsum..cnt */)
{
  __shared__ __align__(16) float    Yl[64 * 128];   // linear dest, 512B/row
  __shared__ __align__(16) _Float16 Mpl[64 * 128];  // 256B/row, 16B slots swizzled by m&7
  __shared__ float Wf[16][65];
  const int tid  = threadIdx.x;
  const int l    = tid & 63;
  const int wv   = tid >> 6;
  const int g    = l >> 4;
  const int col  = l & 15;
  const int n0   = blockIdx.x * 64;

  // --- block 0: zero Bm (1024 f32) + wsum (16) + LT (16) + cnt (16) ---
  if (blockIdx.x == 0) {
    float4 z4 = {0.f, 0.f, 0.f, 0.f};
    float4* p = (float4*)Bm0;
    p[tid] = z4;                       // Bm
    if (tid < 12) p[256 + tid] = z4;   // wsum + LT + cnt region (192 B)
  }

#pragma unroll
  for (int k = 0; k < 8; ++k) {
    const int pr  = wv * 8 + k;
    const int row = pr * 2 + (l >> 5);
    const int q   = l & 31;
    const int b   = (q & ~7) | ((q & 7) ^ (row & 7));
    const float* src = Y + ((size_t)(n0 + row)) * D_OUTC + b * 4;
    __builtin_amdgcn_global_load_lds((const unsigned int*)src,
        (unsigned int*)((char*)&Yl[0] + pr * 1024), 16, 0, 0);
  }
  {
    const int m  = tid >> 2;
    const int dq = tid & 3;
#pragma unroll
    for (int i = 0; i < 4; ++i) {
      const int s = dq * 4 + i;
      const float* mp = Mp + (size_t)m * D_OUTC + s * 8;
      float4 a = *(const float4*)mp;
      float4 b = *(const float4*)(mp + 4);
      FR o;
      o.h[0] = cvt_pkrtz(a.x, a.y); o.h[1] = cvt_pkrtz(a.z, a.w);
      o.h[2] = cvt_pkrtz(b.x, b.y); o.h[3] = cvt_pkrtz(b.z, b.w);
      const int ss = (s & ~7) | ((s & 7) ^ (m & 7));
      *(uint4*)((char*)&Mpl[0] + m * 256 + ss * 16) = o.u;
    }
  }
  {
    const int r  = tid >> 2;
    const int c0 = (tid & 3) * 4;
    float4 wv4 = *(const float4*)(W + (size_t)(n0 + r) * T_CTX + c0);
    Wf[c0 + 0][r] = wv4.x; Wf[c0 + 1][r] = wv4.y;
    Wf[c0 + 2][r] = wv4.z; Wf[c0 + 3][r] = wv4.w;
  }
  __syncthreads();
  {
    const int t = tid >> 4, ni = tid & 15;
    h2 h0 = cvt_pkrtz(Wf[t][4 * ni], Wf[t][4 * ni + 1]);
    h2 h1 = cvt_pkrtz(Wf[t][4 * ni + 2], Wf[t][4 * ni + 3]);
    uint2 pk = {__builtin_bit_cast(unsigned int, h0), __builtin_bit_cast(unsigned int, h1)};
    *(uint2*)(Wt + (size_t)t * N_ROWS + n0 + 4 * ni) = pk;
  }
  f32x4 acc[4];
#pragma unroll
  for (int qi = 0; qi < 4; ++qi) acc[qi] = (f32x4){0.f, 0.f, 0.f, 0.f};
  const int nrow = wv * 16 + col;
#pragma unroll
  for (int ks = 0; ks < 4; ++ks) {
    const char* yb = (const char*)&Yl[0] + nrow * 512 + ks * 128;
    uint4 y0 = *(const uint4*)(yb + 16 * ((2 * g) ^ (nrow & 7)));
    uint4 y1 = *(const uint4*)(yb + 16 * ((2 * g + 1) ^ (nrow & 7)));
    const float* f0 = (const float*)&y0;
    const float* f1 = (const float*)&y1;
    FR B;
    B.h[0] = cvt_pkrtz(f0[0], f0[1]); B.h[1] = cvt_pkrtz(f0[2], f0[3]);
    B.h[2] = cvt_pkrtz(f1[0], f1[1]); B.h[3] = cvt_pkrtz(f1[2], f1[3]);
#pragma unroll
    for (int qi = 0; qi < 4; ++qi) {
      const int m = qi * 16 + col;
      const int s = ks * 4 + g;
      FR A;
      A.u = *(const uint4*)((char*)&Mpl[0] + m * 256 + 16 * ((s & ~7) | ((s & 7) ^ (m & 7))));
      acc[qi] = __builtin_amdgcn_mfma_f32_16x16x32_f16(A.v, B.v, acc[qi], 0, 0, 0);
    }
  }
#pragma unroll
  for (int qi = 0; qi < 4; ++qi)
#pragma unroll
    for (int i = 0; i < 4; ++i)
      Zbt[(size_t)(qi * 16 + g * 4 + i) * N_ROWS + n0 + wv * 16 + col] =
          (_Float16)acc[qi][i];
}

// ================ ss: SS[t] = (w_t.*Z)^T Z  (+B via ones-MFMA) [R15-verbatim] ====
#define SS_NS 256
#define NCH   16
template <bool PARTIAL>
__global__ __launch_bounds__(512, 4) void ss_kernel(
    const _Float16* __restrict__ Zbt, const _Float16* __restrict__ Wt,
    float* __restrict__ SS, float* __restrict__ Bm,
    unsigned short* __restrict__ Pss)
{
  __shared__ __align__(16) _Float16 Zl[4][64 * 64];   // 8KB per buf
  __shared__ __align__(16) _Float16 Wlds[8 * 1024];   // 16KB
  const int tid = threadIdx.x;
  const int l   = tid & 63;
  const int wv  = tid >> 6;
  const int g   = l >> 4;
  const int col = l & 15;
  const int ns  = blockIdx.x & (SS_NS - 1);
  const int cg  = blockIdx.x >> 8;
  const int ctx = cg * 8 + wv;
  const int n0b = ns * 1024;

  f32x4 acc[4][4];
  f32x4 accB[4];
#pragma unroll
  for (int a = 0; a < 4; ++a) {
    accB[a] = (f32x4){0.f, 0.f, 0.f, 0.f};
#pragma unroll
    for (int b = 0; b < 4; ++b) acc[a][b] = (f32x4){0.f, 0.f, 0.f, 0.f};
  }
  FR ones;
#pragma unroll
  for (int j = 0; j < 4; ++j) ones.h[j] = (h2){(_Float16)1.f, (_Float16)1.f};

#pragma unroll
  for (int k = 0; k < 2; ++k) {
    const _Float16* wsrc = Wt + (size_t)ctx * N_ROWS + n0b + k * 512 + l * 8;
    __builtin_amdgcn_global_load_lds((const unsigned int*)wsrc,
        (unsigned int*)((char*)Wlds + wv * 2048 + k * 1024), 16, 0, 0);
  }
  const int zrow  = 8 * wv + (l >> 3);
  const int zslot = l & 7;
  auto stage = [&](int c) {
    const int n0 = n0b + c * 64;
    const _Float16* src = Zbt + (size_t)zrow * N_ROWS + n0 + 8 * (zslot ^ (zrow & 7));
    __builtin_amdgcn_global_load_lds((const unsigned int*)src,
        (unsigned int*)((char*)&Zl[c & 3][0] + wv * 1024 + l * 16), 16, 0, 0);
  };

  stage(0); stage(1); stage(2);
  WAITVM(2);
  SBAR();

  for (int c = 0; c < NCH; ++c) {
    if (c + 3 < NCH) stage(c + 3);
    const char* zb = (const char*)&Zl[c & 3][0];
    const char* wb = (const char*)Wlds + wv * 2048 + c * 128;
#pragma unroll
    for (int s = 0; s < 2; ++s) {
      FR wfr;
      wfr.u = *(const uint4*)(wb + s * 64 + g * 16);
      FR fr[4];
#pragma unroll
      for (int qi = 0; qi < 4; ++qi) {
        const int r = qi * 16 + col;
        fr[qi].u = *(const uint4*)(zb + r * 128 + 16 * ((s * 4 + g) ^ (r & 7)));
      }
      __builtin_amdgcn_s_setprio(1);
#pragma unroll
      for (int qi = 0; qi < 4; ++qi) {
        FR A;
#pragma unroll
        for (int j = 0; j < 4; ++j) A.h[j] = fr[qi].h[j] * wfr.h[j];
        accB[qi] = __builtin_amdgcn_mfma_f32_16x16x32_f16(A.v, ones.v, accB[qi], 0, 0, 0);
#pragma unroll
        for (int ki = 0; ki < 4; ++ki)
          acc[qi][ki] = __builtin_amdgcn_mfma_f32_16x16x32_f16(A.v, fr[ki].v, acc[qi][ki], 0, 0, 0);
      }
      __builtin_amdgcn_s_setprio(0);
    }
    if (c + 3 < NCH)       { WAITVM(2); SBAR(); }
    else if (c == NCH - 3) { WAITVM(1); SBAR(); }
    else if (c == NCH - 2) { WAITVM(0); SBAR(); }
  }

  if (col == 0) {
#pragma unroll
    for (int qi = 0; qi < 4; ++qi)
#pragma unroll
      for (int i = 0; i < 4; ++i)
        atomicAdd(&Bm[ctx * 64 + qi * 16 + g * 4 + i], accB[qi][i]);
  }
  if (PARTIAL) {
    unsigned short* P = Pss + ((size_t)ns * 16 + ctx) * 4096;
#pragma unroll
    for (int qi = 0; qi < 4; ++qi)
#pragma unroll
      for (int ki = 0; ki < 4; ++ki)
#pragma unroll
        for (int i = 0; i < 4; ++i)
          P[(qi * 16 + g * 4 + i) * 64 + ki * 16 + col] = f2bf(acc[qi][ki][i]);
  } else {
#pragma unroll
    for (int qi = 0; qi < 4; ++qi)
#pragma unroll
      for (int ki = 0; ki < 4; ++ki)
#pragma unroll
        for (int i = 0; i < 4; ++i)
          atomicAdd(&SS[(size_t)ctx * 4096 + (qi * 16 + g * 4 + i) * 64 + ki * 16 + col],
                    acc[qi][ki][i]);
  }
}

// ================ ssredfin: ssred (256 blk) + wsum (64 blk) + last-block finalize ====
__global__ __launch_bounds__(256) void ssredfin_kernel(
    const unsigned short* __restrict__ Pss, float* __restrict__ SS,
    const _Float16* __restrict__ Wt, float* __restrict__ wsum,
    const float* __restrict__ Bm, const float* __restrict__ Cp,
    const float* __restrict__ emaS, const unsigned char* __restrict__ inited,
    float* __restrict__ out, unsigned int* __restrict__ cnt)
{
  const int tid = threadIdx.x;
  if (blockIdx.x < 256) {
    const int e = blockIdx.x * 256 + tid;
    float s = 0.f;
#pragma unroll 8
    for (int b = 0; b < 256; ++b)
      s += bf2f(Pss[(size_t)b * 65536 + e]);
    SS[e] = s;
  } else {
    const int b2 = blockIdx.x - 256;     // 0..63
    const int t = b2 >> 2, q = b2 & 3;
    const uint4* base = (const uint4*)(Wt + (size_t)t * N_ROWS + q * 65536);
    const h2 one2 = {(_Float16)1.f, (_Float16)1.f};
    float s = 0.f;
    for (int i = tid; i < 8192; i += 256) {
      uint4 v = base[i];
      const h2* h = (const h2*)&v;
#pragma unroll
      for (int j = 0; j < 4; ++j) s = fdot2f(h[j], one2, s);
    }
    s += __shfl_xor(s, 1);  s += __shfl_xor(s, 2);
    s += __shfl_xor(s, 4);  s += __shfl_xor(s, 8);
    s += __shfl_xor(s, 16); s += __shfl_xor(s, 32);
    __shared__ float redw[4];
    if ((tid & 63) == 0) redw[tid >> 6] = s;
    __syncthreads();
    if (tid == 0) atomicAdd(&wsum[t], redw[0] + redw[1] + redw[2] + redw[3]);
  }

  // ---- ticket: last block finalizes ----
  __threadfence();
  __shared__ unsigned int ticket;
  if (tid == 0) ticket = atomicAdd(cnt, 1u);
  __syncthreads();
  if (ticket != 319u) return;
  __threadfence();   // acquire: SS / wsum written by other blocks now visible

  __shared__ float wsl[16];
  __shared__ float muL[64], stdL[64];
  __shared__ float bred[4];
  if (tid < 16) wsl[tid] = wsum[tid];
  __syncthreads();
  float out_acc = 0.f, act_cnt = 0.f;
  for (int t = 0; t < 16; ++t) {
    const float ws  = wsl[t];
    const float inv = 1.0f / ws;
    if (tid < 64) {
      float mu  = Bm[t * 64 + tid] * inv;
      float Smm = SS[(size_t)t * 4096 + tid * 65] * inv - mu * mu;
      float de  = 0.9f * emaS[(size_t)t * 4096 + tid * 65] + 0.1f * Smm;
      float sq  = inited[t] ? de : Smm;
      muL[tid]  = mu;
      stdL[tid] = sqrtf(sq + 1e-6f);
    }
    __syncthreads();
    const int m  = tid >> 2;
    const int k0 = (tid & 3) * 16;
    const float* SSr = SS + (size_t)t * 4096 + m * 64;
    const float* Cpr = Cp + (size_t)t * 4096 + m * 64;
    float acc = 0.f;
#pragma unroll
    for (int j = 0; j < 16; ++j) {
      const int k = k0 + j;
      float Sig = SSr[k] * inv - muL[m] * muL[k];
      float den = stdL[m] * stdL[k] + 1e-6f;
      float ch  = fminf(1.f, fmaxf(-1.f, Sig / den));
      float d   = ch - Cpr[k];
      acc = fmaf(d, d, acc);
    }
#pragma unroll
    for (int o = 1; o < 64; o <<= 1) acc += __shfl_xor(acc, o);
    if ((tid & 63) == 0) bred[tid >> 6] = acc;
    __syncthreads();
    if (tid == 0) {
      float lt = (bred[0] + bred[1] + bred[2] + bred[3]) * inv;
      if (ws >= 30.0f) { out_acc += lt; act_cnt += 1.f; }
    }
    __syncthreads();
  }
  if (tid == 0) out[0] = (act_cnt > 0.f) ? (0.1f * out_acc / act_cnt) : 0.f;
}

// ================ fallback-path kernels (small ws) ================
__global__ __launch_bounds__(256) void wsk_kernel(const _Float16* __restrict__ Wt,
                                                  float* __restrict__ wsum)
{
  const int tid = threadIdx.x;
  const int t = blockIdx.x >> 2, q = blockIdx.x & 3;
  const uint4* base = (const uint4*)(Wt + (size_t)t * N_ROWS + q * 65536);
  const h2 one2 = {(_Float16)1.f, (_Float16)1.f};
  float s = 0.f;
  for (int i = tid; i < 8192; i += 256) {
    uint4 v = base[i];
    const h2* h = (const h2*)&v;
#pragma unroll
    for (int j = 0; j < 4; ++j) s = fdot2f(h[j], one2, s);
  }
  s += __shfl_xor(s, 1);  s += __shfl_xor(s, 2);
  s += __shfl_xor(s, 4);  s += __shfl_xor(s, 8);
  s += __shfl_xor(s, 16); s += __shfl_xor(s, 32);
  __shared__ float red[4];
  if ((tid & 63) == 0) red[tid >> 6] = s;
  __syncthreads();
  if (tid == 0) atomicAdd(&wsum[t], red[0] + red[1] + red[2] + red[3]);
}

__global__ __launch_bounds__(64) void fin1_kernel(
    const float* __restrict__ SS, const float* __restrict__ Bm,
    const float* __restrict__ wsum, const float* __restrict__ Cp,
    const float* __restrict__ emaS, const unsigned char* __restrict__ inited,
    float* __restrict__ LT)
{
  const int t = blockIdx.x, m = threadIdx.x;
  __shared__ float muL[64], stdL[64];
  const float ws  = wsum[t];
  const float inv = 1.0f / ws;
  const float mu  = Bm[t * 64 + m] * inv;
  {
    float Smm = SS[(size_t)t * 4096 + m * 65] * inv - mu * mu;
    float de  = 0.9f * emaS[(size_t)t * 4096 + m * 65] + 0.1f * Smm;
    float sq  = inited[t] ? de : Smm;
    muL[m]  = mu;
    stdL[m] = sqrtf(sq + 1e-6f);
  }
  __syncthreads();
  const float sm = stdL[m];
  const float* SSr = SS + (size_t)t * 4096 + m * 64;
  const float* Cpr = Cp + (size_t)t * 4096 + m * 64;
  float acc = 0.f;
#pragma unroll
  for (int k = 0; k < 64; ++k) {
    float Sig = SSr[k] * inv - mu * muL[k];
    float den = sm * stdL[k] + 1e-6f;
    float ch  = fminf(1.f, fmaxf(-1.f, Sig / den));
    float d   = ch - Cpr[k];
    acc = fmaf(d, d, acc);
  }
#pragma unroll
  for (int o = 1; o < 64; o <<= 1) acc += __shfl_xor(acc, o);
  if (m == 0) LT[t] = acc * inv;
}

__global__ __launch_bounds__(64) void fin2_kernel(
    const float* __restrict__ LT, const float* __restrict__ wsum,
    float* __restrict__ out)
{
  const int l = threadIdx.x;
  float lt = 0.f, act = 0.f;
  if (l < 16) {
    float ws = wsum[l];
    if (ws >= 30.0f) { act = 1.f; lt = LT[l]; }
  }
#pragma unroll
  for (int o = 1; o < 16; o <<= 1) {
    lt  += __shfl_xor(lt, o);
    act += __shfl_xor(act, o);
  }
  if (l == 0) out[0] = (act > 0.f) ? (0.1f * 1.0f * lt / act) : 0.f;
}

extern "C" void kernel_launch(void* const* d_in, const int* in_sizes, int n_in,
                              void* d_out, int out_size, void* d_ws, size_t ws_size,
                              hipStream_t stream) {
  (void)in_sizes; (void)n_in; (void)out_size;
  const float* Y    = (const float*)d_in[0];
  const float* W    = (const float*)d_in[1];
  const float* Mp   = (const float*)d_in[2];
  const float* Cp   = (const float*)d_in[3];
  const float* emaS = (const float*)d_in[4];
  const unsigned char* inited = (const unsigned char*)d_in[6];
  float* out = (float*)d_out;
  char* ws = (char*)d_ws;
  _Float16* Zbt = (_Float16*)(ws + ZB_OFF);
  _Float16* Wt  = (_Float16*)(ws + WT_OFF);
  float* SS   = (float*)(ws + SS_OFF);
  float* Bm   = (float*)(ws + B_OFF);
  float* wsum = (float*)(ws + WSUM_OFF);
  float* LT   = (float*)(ws + LT_OFF);
  unsigned int* cnt = (unsigned int*)(ws + CNT_OFF);
  unsigned short* Pss = (unsigned short*)(ws + PSS_OFF);

  if (ws_size >= NEED_BIG) {
    // 3 launches: zk (zeroes Bm/wsum/cnt), ss, ssredfin (ssred + wsum + finalize)
    zk_kernel<<<N_ROWS / 64, 256, 0, stream>>>(Y, Mp, W, Zbt, Wt, Bm);
    ss_kernel<true><<<2 * SS_NS, 512, 0, stream>>>(Zbt, Wt, SS, Bm, Pss);
    ssredfin_kernel<<<320, 256, 0, stream>>>(Pss, SS, Wt, wsum, Bm, Cp, emaS,
                                             inited, out, cnt);
  } else {
    (void)hipMemsetAsync(ws + SS_OFF, 0, SS_BYTES, stream);
    zk_kernel<<<N_ROWS / 64, 256, 0, stream>>>(Y, Mp, W, Zbt, Wt, Bm);
    ss_kernel<false><<<2 * SS_NS, 512, 0, stream>>>(Zbt, Wt, SS, Bm, Pss);
    wsk_kernel<<<64, 256, 0, stream>>>(Wt, wsum);
    fin1_kernel<<<16, 64, 0, stream>>>(SS, Bm, wsum, Cp, emaS, inited, LT);
    fin2_kernel<<<1, 64, 0, stream>>>(LT, wsum, out);
  }
}

// Round 19
// 126.716 us; speedup vs baseline: 1.4154x; 1.4154x over previous
//
#include <hip/hip_runtime.h>
#include <stdint.h>

#define N_ROWS 262144
#define D_OUTC 128
#define M_MOD  64
#define T_CTX  16

// ---- workspace layout (bytes) ----
#define ZB_OFF   ((size_t)0)
#define ZB_BYTES ((size_t)M_MOD * N_ROWS * 2)          // Zbt[m][n] f16  33.5MB
#define WT_OFF   (ZB_OFF + ZB_BYTES)
#define WT_BYTES ((size_t)T_CTX * N_ROWS * 2)          // Wt[t][n] f16  8.4MB
#define SS_OFF   (WT_OFF + WT_BYTES)
#define SS_BYTES ((size_t)T_CTX * M_MOD * M_MOD * 4)
#define B_OFF    (SS_OFF + SS_BYTES)
#define B_BYTES  ((size_t)T_CTX * M_MOD * 4)
#define WSUM_OFF (B_OFF + B_BYTES)
#define WSUM_BYTES ((size_t)64)
#define LT_OFF   (WSUM_OFF + WSUM_BYTES)
#define LT_BYTES ((size_t)64)
#define PSS_OFF  (LT_OFF + LT_BYTES)
#define PSS_BYTES ((size_t)256 * T_CTX * M_MOD * M_MOD * 2)  // 33.5MB bf16 partials
#define NEED_BIG (PSS_OFF + PSS_BYTES)

typedef __attribute__((ext_vector_type(4))) float f32x4;
typedef __attribute__((ext_vector_type(8))) _Float16 f16x8;
typedef __attribute__((ext_vector_type(2))) _Float16 h2;

union FR { uint4 u; f16x8 v; h2 h[4]; };

__device__ __forceinline__ float bf2f(unsigned short u) {
  return __uint_as_float(((unsigned int)u) << 16);
}
__device__ __forceinline__ unsigned short f2bf(float f) {
  unsigned int x = __float_as_uint(f);
  return (unsigned short)((x + 0x7fffu + ((x >> 16) & 1u)) >> 16);
}
__device__ __forceinline__ h2 cvt_pkrtz(float a, float b) {
  return __builtin_bit_cast(h2, __builtin_amdgcn_cvt_pkrtz(a, b));
}
#if __has_builtin(__builtin_amdgcn_fdot2)
__device__ __forceinline__ float fdot2f(h2 a, h2 b, float c) {
  return __builtin_amdgcn_fdot2(a, b, c, false);
}
#else
__device__ __forceinline__ float fdot2f(h2 a, h2 b, float c) {
  return c + (float)a[0] * (float)b[0] + (float)a[1] * (float)b[1];
}
#endif

#define WAITVM(N) asm volatile("s_waitcnt vmcnt(" #N ")" ::: "memory")
#define SBAR() do { __builtin_amdgcn_s_barrier(); __builtin_amdgcn_sched_barrier(0); } while (0)

// ================ zk: Z^T = (Mp @ Y^T) via f16 MFMA; also Wt; block 0 zeroes Bm/wsum ====
__global__ __launch_bounds__(256, 3) void zk_kernel(
    const float* __restrict__ Y, const float* __restrict__ Mp,
    const float* __restrict__ W,
    _Float16* __restrict__ Zbt, _Float16* __restrict__ Wt,
    float* __restrict__ Bm0 /* Bm..wsum, 4160 B */)
{
  __shared__ __align__(16) float    Yl[64 * 128];   // linear dest, 512B/row
  __shared__ __align__(16) _Float16 Mpl[64 * 128];  // 256B/row, 16B slots swizzled by m&7
  __shared__ float Wf[16][65];
  const int tid  = threadIdx.x;
  const int l    = tid & 63;
  const int wv   = tid >> 6;
  const int g    = l >> 4;
  const int col  = l & 15;
  const int n0   = blockIdx.x * 64;

  // --- block 0: zero Bm (1024 f32) + wsum (16 f32) for the downstream atomics ---
  if (blockIdx.x == 0) {
    float4 z4 = {0.f, 0.f, 0.f, 0.f};
    float4* p = (float4*)Bm0;
    p[tid] = z4;                 // 256 float4 = Bm
    if (tid < 4) p[256 + tid] = z4;   // wsum
  }

#pragma unroll
  for (int k = 0; k < 8; ++k) {
    const int pr  = wv * 8 + k;
    const int row = pr * 2 + (l >> 5);
    const int q   = l & 31;
    const int b   = (q & ~7) | ((q & 7) ^ (row & 7));
    const float* src = Y + ((size_t)(n0 + row)) * D_OUTC + b * 4;
    __builtin_amdgcn_global_load_lds((const unsigned int*)src,
        (unsigned int*)((char*)&Yl[0] + pr * 1024), 16, 0, 0);
  }
  {
    const int m  = tid >> 2;
    const int dq = tid & 3;
#pragma unroll
    for (int i = 0; i < 4; ++i) {
      const int s = dq * 4 + i;
      const float* mp = Mp + (size_t)m * D_OUTC + s * 8;
      float4 a = *(const float4*)mp;
      float4 b = *(const float4*)(mp + 4);
      FR o;
      o.h[0] = cvt_pkrtz(a.x, a.y); o.h[1] = cvt_pkrtz(a.z, a.w);
      o.h[2] = cvt_pkrtz(b.x, b.y); o.h[3] = cvt_pkrtz(b.z, b.w);
      const int ss = (s & ~7) | ((s & 7) ^ (m & 7));
      *(uint4*)((char*)&Mpl[0] + m * 256 + ss * 16) = o.u;
    }
  }
  {
    const int r  = tid >> 2;
    const int c0 = (tid & 3) * 4;
    float4 wv4 = *(const float4*)(W + (size_t)(n0 + r) * T_CTX + c0);
    Wf[c0 + 0][r] = wv4.x; Wf[c0 + 1][r] = wv4.y;
    Wf[c0 + 2][r] = wv4.z; Wf[c0 + 3][r] = wv4.w;
  }
  __syncthreads();
  {
    const int t = tid >> 4, ni = tid & 15;
    h2 h0 = cvt_pkrtz(Wf[t][4 * ni], Wf[t][4 * ni + 1]);
    h2 h1 = cvt_pkrtz(Wf[t][4 * ni + 2], Wf[t][4 * ni + 3]);
    uint2 pk = {__builtin_bit_cast(unsigned int, h0), __builtin_bit_cast(unsigned int, h1)};
    *(uint2*)(Wt + (size_t)t * N_ROWS + n0 + 4 * ni) = pk;
  }
  f32x4 acc[4];
#pragma unroll
  for (int qi = 0; qi < 4; ++qi) acc[qi] = (f32x4){0.f, 0.f, 0.f, 0.f};
  const int nrow = wv * 16 + col;
#pragma unroll
  for (int ks = 0; ks < 4; ++ks) {
    const char* yb = (const char*)&Yl[0] + nrow * 512 + ks * 128;
    uint4 y0 = *(const uint4*)(yb + 16 * ((2 * g) ^ (nrow & 7)));
    uint4 y1 = *(const uint4*)(yb + 16 * ((2 * g + 1) ^ (nrow & 7)));
    const float* f0 = (const float*)&y0;
    const float* f1 = (const float*)&y1;
    FR B;
    B.h[0] = cvt_pkrtz(f0[0], f0[1]); B.h[1] = cvt_pkrtz(f0[2], f0[3]);
    B.h[2] = cvt_pkrtz(f1[0], f1[1]); B.h[3] = cvt_pkrtz(f1[2], f1[3]);
#pragma unroll
    for (int qi = 0; qi < 4; ++qi) {
      const int m = qi * 16 + col;
      const int s = ks * 4 + g;
      FR A;
      A.u = *(const uint4*)((char*)&Mpl[0] + m * 256 + 16 * ((s & ~7) | ((s & 7) ^ (m & 7))));
      acc[qi] = __builtin_amdgcn_mfma_f32_16x16x32_f16(A.v, B.v, acc[qi], 0, 0, 0);
    }
  }
#pragma unroll
  for (int qi = 0; qi < 4; ++qi)
#pragma unroll
    for (int i = 0; i < 4; ++i)
      Zbt[(size_t)(qi * 16 + g * 4 + i) * N_ROWS + n0 + wv * 16 + col] =
          (_Float16)acc[qi][i];
}

// ================ ss: SS[t] = (w_t.*Z)^T Z  (+B via ones-MFMA) [R15-verbatim] ====
#define SS_NS 256
#define NCH   16
template <bool PARTIAL>
__global__ __launch_bounds__(512, 4) void ss_kernel(
    const _Float16* __restrict__ Zbt, const _Float16* __restrict__ Wt,
    float* __restrict__ SS, float* __restrict__ Bm,
    unsigned short* __restrict__ Pss)
{
  __shared__ __align__(16) _Float16 Zl[4][64 * 64];   // 8KB per buf
  __shared__ __align__(16) _Float16 Wlds[8 * 1024];   // 16KB
  const int tid = threadIdx.x;
  const int l   = tid & 63;
  const int wv  = tid >> 6;
  const int g   = l >> 4;
  const int col = l & 15;
  const int ns  = blockIdx.x & (SS_NS - 1);
  const int cg  = blockIdx.x >> 8;
  const int ctx = cg * 8 + wv;
  const int n0b = ns * 1024;

  f32x4 acc[4][4];
  f32x4 accB[4];
#pragma unroll
  for (int a = 0; a < 4; ++a) {
    accB[a] = (f32x4){0.f, 0.f, 0.f, 0.f};
#pragma unroll
    for (int b = 0; b < 4; ++b) acc[a][b] = (f32x4){0.f, 0.f, 0.f, 0.f};
  }
  FR ones;
#pragma unroll
  for (int j = 0; j < 4; ++j) ones.h[j] = (h2){(_Float16)1.f, (_Float16)1.f};

#pragma unroll
  for (int k = 0; k < 2; ++k) {
    const _Float16* wsrc = Wt + (size_t)ctx * N_ROWS + n0b + k * 512 + l * 8;
    __builtin_amdgcn_global_load_lds((const unsigned int*)wsrc,
        (unsigned int*)((char*)Wlds + wv * 2048 + k * 1024), 16, 0, 0);
  }
  const int zrow  = 8 * wv + (l >> 3);
  const int zslot = l & 7;
  auto stage = [&](int c) {
    const int n0 = n0b + c * 64;
    const _Float16* src = Zbt + (size_t)zrow * N_ROWS + n0 + 8 * (zslot ^ (zrow & 7));
    __builtin_amdgcn_global_load_lds((const unsigned int*)src,
        (unsigned int*)((char*)&Zl[c & 3][0] + wv * 1024 + l * 16), 16, 0, 0);
  };

  stage(0); stage(1); stage(2);
  WAITVM(2);
  SBAR();

  for (int c = 0; c < NCH; ++c) {
    if (c + 3 < NCH) stage(c + 3);
    const char* zb = (const char*)&Zl[c & 3][0];
    const char* wb = (const char*)Wlds + wv * 2048 + c * 128;
#pragma unroll
    for (int s = 0; s < 2; ++s) {
      FR wfr;
      wfr.u = *(const uint4*)(wb + s * 64 + g * 16);
      FR fr[4];
#pragma unroll
      for (int qi = 0; qi < 4; ++qi) {
        const int r = qi * 16 + col;
        fr[qi].u = *(const uint4*)(zb + r * 128 + 16 * ((s * 4 + g) ^ (r & 7)));
      }
      __builtin_amdgcn_s_setprio(1);
#pragma unroll
      for (int qi = 0; qi < 4; ++qi) {
        FR A;
#pragma unroll
        for (int j = 0; j < 4; ++j) A.h[j] = fr[qi].h[j] * wfr.h[j];
        accB[qi] = __builtin_amdgcn_mfma_f32_16x16x32_f16(A.v, ones.v, accB[qi], 0, 0, 0);
#pragma unroll
        for (int ki = 0; ki < 4; ++ki)
          acc[qi][ki] = __builtin_amdgcn_mfma_f32_16x16x32_f16(A.v, fr[ki].v, acc[qi][ki], 0, 0, 0);
      }
      __builtin_amdgcn_s_setprio(0);
    }
    if (c + 3 < NCH)       { WAITVM(2); SBAR(); }
    else if (c == NCH - 3) { WAITVM(1); SBAR(); }
    else if (c == NCH - 2) { WAITVM(0); SBAR(); }
  }

  if (col == 0) {
#pragma unroll
    for (int qi = 0; qi < 4; ++qi)
#pragma unroll
      for (int i = 0; i < 4; ++i)
        atomicAdd(&Bm[ctx * 64 + qi * 16 + g * 4 + i], accB[qi][i]);
  }
  if (PARTIAL) {
    unsigned short* P = Pss + ((size_t)ns * 16 + ctx) * 4096;
#pragma unroll
    for (int qi = 0; qi < 4; ++qi)
#pragma unroll
      for (int ki = 0; ki < 4; ++ki)
#pragma unroll
        for (int i = 0; i < 4; ++i)
          P[(qi * 16 + g * 4 + i) * 64 + ki * 16 + col] = f2bf(acc[qi][ki][i]);
  } else {
#pragma unroll
    for (int qi = 0; qi < 4; ++qi)
#pragma unroll
      for (int ki = 0; ki < 4; ++ki)
#pragma unroll
        for (int i = 0; i < 4; ++i)
          atomicAdd(&SS[(size_t)ctx * 4096 + (qi * 16 + g * 4 + i) * 64 + ki * 16 + col],
                    acc[qi][ki][i]);
  }
}

// ================ ssredw: [bid<256] reduce Pss -> SS ; [else] wsum from Wt ================
__global__ __launch_bounds__(256) void ssredw_kernel(
    const unsigned short* __restrict__ Pss, float* __restrict__ SS,
    const _Float16* __restrict__ Wt, float* __restrict__ wsum)
{
  const int tid = threadIdx.x;
  if (blockIdx.x < 256) {
    const int e = blockIdx.x * 256 + tid;
    float s = 0.f;
#pragma unroll 8
    for (int b = 0; b < 256; ++b)
      s += bf2f(Pss[(size_t)b * 65536 + e]);
    SS[e] = s;
  } else {
    const int b2 = blockIdx.x - 256;     // 0..63
    const int t = b2 >> 2, q = b2 & 3;
    const uint4* base = (const uint4*)(Wt + (size_t)t * N_ROWS + q * 65536);
    const h2 one2 = {(_Float16)1.f, (_Float16)1.f};
    float s = 0.f;
    for (int i = tid; i < 8192; i += 256) {
      uint4 v = base[i];
      const h2* h = (const h2*)&v;
#pragma unroll
      for (int j = 0; j < 4; ++j) s = fdot2f(h[j], one2, s);
    }
    s += __shfl_xor(s, 1);  s += __shfl_xor(s, 2);
    s += __shfl_xor(s, 4);  s += __shfl_xor(s, 8);
    s += __shfl_xor(s, 16); s += __shfl_xor(s, 32);
    __shared__ float red[4];
    if ((tid & 63) == 0) red[tid >> 6] = s;
    __syncthreads();
    if (tid == 0) atomicAdd(&wsum[t], red[0] + red[1] + red[2] + red[3]);
  }
}

// ================ wsk (standalone, small-ws fallback path only) ================
__global__ __launch_bounds__(256) void wsk_kernel(const _Float16* __restrict__ Wt,
                                                  float* __restrict__ wsum)
{
  const int tid = threadIdx.x;
  const int t = blockIdx.x >> 2, q = blockIdx.x & 3;
  const uint4* base = (const uint4*)(Wt + (size_t)t * N_ROWS + q * 65536);
  const h2 one2 = {(_Float16)1.f, (_Float16)1.f};
  float s = 0.f;
  for (int i = tid; i < 8192; i += 256) {
    uint4 v = base[i];
    const h2* h = (const h2*)&v;
#pragma unroll
    for (int j = 0; j < 4; ++j) s = fdot2f(h[j], one2, s);
  }
  s += __shfl_xor(s, 1);  s += __shfl_xor(s, 2);
  s += __shfl_xor(s, 4);  s += __shfl_xor(s, 8);
  s += __shfl_xor(s, 16); s += __shfl_xor(s, 32);
  __shared__ float red[4];
  if ((tid & 63) == 0) red[tid >> 6] = s;
  __syncthreads();
  if (tid == 0) atomicAdd(&wsum[t], red[0] + red[1] + red[2] + red[3]);
}

// ================ finalize ================
__global__ __launch_bounds__(64) void fin1_kernel(
    const float* __restrict__ SS, const float* __restrict__ Bm,
    const float* __restrict__ wsum, const float* __restrict__ Cp,
    const float* __restrict__ emaS, const unsigned char* __restrict__ inited,
    float* __restrict__ LT)
{
  const int t = blockIdx.x, m = threadIdx.x;
  __shared__ float muL[64], stdL[64];
  const float ws  = wsum[t];
  const float inv = 1.0f / ws;
  const float mu  = Bm[t * 64 + m] * inv;
  {
    float Smm = SS[(size_t)t * 4096 + m * 65] * inv - mu * mu;
    float de  = 0.9f * emaS[(size_t)t * 4096 + m * 65] + 0.1f * Smm;
    float sq  = inited[t] ? de : Smm;
    muL[m]  = mu;
    stdL[m] = sqrtf(sq + 1e-6f);
  }
  __syncthreads();
  const float sm = stdL[m];
  const float* SSr = SS + (size_t)t * 4096 + m * 64;
  const float* Cpr = Cp + (size_t)t * 4096 + m * 64;
  float acc = 0.f;
#pragma unroll
  for (int k = 0; k < 64; ++k) {
    float Sig = SSr[k] * inv - mu * muL[k];
    float den = sm * stdL[k] + 1e-6f;
    float ch  = fminf(1.f, fmaxf(-1.f, Sig / den));
    float d   = ch - Cpr[k];
    acc = fmaf(d, d, acc);
  }
#pragma unroll
  for (int o = 1; o < 64; o <<= 1) acc += __shfl_xor(acc, o);
  if (m == 0) LT[t] = acc * inv;
}

__global__ __launch_bounds__(64) void fin2_kernel(
    const float* __restrict__ LT, const float* __restrict__ wsum,
    float* __restrict__ out)
{
  const int l = threadIdx.x;
  float lt = 0.f, act = 0.f;
  if (l < 16) {
    float ws = wsum[l];
    if (ws >= 30.0f) { act = 1.f; lt = LT[l]; }
  }
#pragma unroll
  for (int o = 1; o < 16; o <<= 1) {
    lt  += __shfl_xor(lt, o);
    act += __shfl_xor(act, o);
  }
  if (l == 0) out[0] = (act > 0.f) ? (0.1f * 1.0f * lt / act) : 0.f;
}

extern "C" void kernel_launch(void* const* d_in, const int* in_sizes, int n_in,
                              void* d_out, int out_size, void* d_ws, size_t ws_size,
                              hipStream_t stream) {
  (void)in_sizes; (void)n_in; (void)out_size;
  const float* Y    = (const float*)d_in[0];
  const float* W    = (const float*)d_in[1];
  const float* Mp   = (const float*)d_in[2];
  const float* Cp   = (const float*)d_in[3];
  const float* emaS = (const float*)d_in[4];
  const unsigned char* inited = (const unsigned char*)d_in[6];
  float* out = (float*)d_out;
  char* ws = (char*)d_ws;
  _Float16* Zbt = (_Float16*)(ws + ZB_OFF);
  _Float16* Wt  = (_Float16*)(ws + WT_OFF);
  float* SS   = (float*)(ws + SS_OFF);
  float* Bm   = (float*)(ws + B_OFF);
  float* wsum = (float*)(ws + WSUM_OFF);
  float* LT   = (float*)(ws + LT_OFF);
  unsigned short* Pss = (unsigned short*)(ws + PSS_OFF);

  if (ws_size >= NEED_BIG) {
    // 5 launches: zk (incl. Bm/wsum zero), ss, ssredw (ssred + wsk), fin1, fin2
    zk_kernel<<<N_ROWS / 64, 256, 0, stream>>>(Y, Mp, W, Zbt, Wt, Bm);
    ss_kernel<true><<<2 * SS_NS, 512, 0, stream>>>(Zbt, Wt, SS, Bm, Pss);
    ssredw_kernel<<<320, 256, 0, stream>>>(Pss, SS, Wt, wsum);
  } else {
    (void)hipMemsetAsync(ws + SS_OFF, 0, SS_BYTES, stream);
    zk_kernel<<<N_ROWS / 64, 256, 0, stream>>>(Y, Mp, W, Zbt, Wt, Bm);
    ss_kernel<false><<<2 * SS_NS, 512, 0, stream>>>(Zbt, Wt, SS, Bm, Pss);
    wsk_kernel<<<64, 256, 0, stream>>>(Wt, wsum);
  }
  fin1_kernel<<<16, 64, 0, stream>>>(SS, Bm, wsum, Cp, emaS, inited, LT);
  fin2_kernel<<<1, 64, 0, stream>>>(LT, wsum, out);
}